// Round 4
// baseline (104.058 us; speedup 1.0000x reference)
//
#include <hip/hip_runtime.h>

constexpr int EMB    = 300;
constexpr int EMB4   = 75;     // EMB / 4 (float4 chunks per row)
constexpr int HIDDEN = 512;
constexpr int SEQ    = 512;
constexpr int BATCH  = 1024;
constexpr int VOCAB  = 50000;
constexpr int NBUK   = 32;     // vocab buckets
constexpr int BDIV   = 1563;   // ceil(50000/32); 49999/1563 = 31
constexpr int GBATCH = 8;      // batches per pool block
constexpr int GBM    = 16;     // batches per fc1 block

__device__ __forceinline__ float4 f4add(float4 a, float4 b) {
    return make_float4(a.x + b.x, a.y + b.y, a.z + b.z, a.w + b.w);
}

// ---------------- Kernel 1: bucketize tokens per batch (deterministic) -------
// One wave per batch. Stable counting sort of the batch's tokens into NBUK
// vocab buckets using ballot-based ranks (no atomics -> bitwise deterministic).
// Output: btok[b][SEQ] tokens grouped by bucket (original order preserved
// within bucket), boff[b][NBUK+1] CSR offsets.
__global__ __launch_bounds__(256) void bucketize_kernel(
    const int* __restrict__ text,      // [SEQ, BATCH]
    const int* __restrict__ lengths,   // [BATCH]
    int* __restrict__ btok,            // [BATCH, SEQ]
    int* __restrict__ boff)            // [BATCH, NBUK+1]
{
    const int wave = threadIdx.x >> 6;
    const int lane = threadIdx.x & 63;
    const int b    = blockIdx.x * 4 + wave;
    const int len  = lengths[b];
    const unsigned long long ltmask = (1ull << lane) - 1ull;

    // pass 1: per-bucket counts (lane k<NBUK holds count of bucket k)
    int cnt = 0;
#pragma unroll
    for (int c = 0; c < 8; ++c) {
        const int s = c * 64 + lane;
        int k = NBUK;  // invalid bucket for padding lanes
        if (s < len) k = text[(size_t)s * BATCH + b] / BDIV;
        for (int kk = 0; kk < NBUK; ++kk) {
            const unsigned long long m = __ballot(k == kk);
            if (lane == kk) cnt += __popcll(m);
        }
    }
    // exclusive prefix over lanes 0..31
    int incl = cnt;
#pragma unroll
    for (int off = 1; off < 32; off <<= 1) {
        const int v = __shfl_up(incl, off);
        if (lane >= off && lane < NBUK) incl += v;
    }
    const int excl = incl - cnt;
    if (lane < NBUK)  boff[b * (NBUK + 1) + lane] = excl;
    if (lane == NBUK - 1) boff[b * (NBUK + 1) + NBUK] = incl;

    // pass 2: stable scatter
    int base = excl;   // valid on lanes < NBUK
#pragma unroll
    for (int c = 0; c < 8; ++c) {
        const int s = c * 64 + lane;
        int tok = 0, k = NBUK;
        if (s < len) { tok = text[(size_t)s * BATCH + b]; k = tok / BDIV; }
        unsigned long long mym = 0;
        int chunkcnt = 0;
        for (int kk = 0; kk < NBUK; ++kk) {
            const unsigned long long m = __ballot(k == kk);
            if (k == kk) mym = m;
            if (lane == kk) chunkcnt = __popcll(m);
        }
        const int rank = __popcll(mym & ltmask);
        const int pos  = __shfl(base, k) + rank;
        if (s < len) btok[(size_t)b * SEQ + pos] = tok;
        base += chunkcnt;
    }
}

// ---------------- Kernel 2: bucketed gather + pool (partial sums) ------------
// Grid NX * (BATCH/GBATCH). Slot x = blockIdx%NX (~XCD id via round-robin
// dispatch). Slot x handles buckets k = x + j*NX in ascending j, so each
// XCD's live gather working set is ~1.9 MB (< 4 MB L2) per phase.
// 320 threads = 4 groups x 80 (75 active float4 lanes); group owns 2 batches.
__device__ __forceinline__ void acc_range(
    const float* __restrict__ emb, const int* __restrict__ btok,
    int base, int lo, int hi, int c, float4& A)
{
    int i = lo;
    for (; i + 4 <= hi; i += 4) {
        const int t0 = btok[base + i + 0];
        const int t1 = btok[base + i + 1];
        const int t2 = btok[base + i + 2];
        const int t3 = btok[base + i + 3];
        const float4 v0 = ((const float4*)(emb + (size_t)t0 * EMB))[c];
        const float4 v1 = ((const float4*)(emb + (size_t)t1 * EMB))[c];
        const float4 v2 = ((const float4*)(emb + (size_t)t2 * EMB))[c];
        const float4 v3 = ((const float4*)(emb + (size_t)t3 * EMB))[c];
        A = f4add(A, f4add(f4add(v0, v1), f4add(v2, v3)));
    }
    for (; i < hi; ++i) {
        const int t = btok[base + i];
        A = f4add(A, ((const float4*)(emb + (size_t)t * EMB))[c]);
    }
}

__global__ __launch_bounds__(320) void pool_kernel(
    const int* __restrict__ btok,      // [BATCH, SEQ] bucket-grouped
    const int* __restrict__ boff,      // [BATCH, NBUK+1]
    const float* __restrict__ emb,     // [VOCAB, EMB]
    float* __restrict__ partial,       // [NX, BATCH, EMB]
    int NX)
{
    const int x     = blockIdx.x % NX;
    const int g     = blockIdx.x / NX;
    const int group = threadIdx.x / 80;
    const int c     = threadIdx.x % 80;
    if (c >= EMB4) return;             // no barriers below: safe early-exit

    const int b0 = g * GBATCH + group * 2;   // this group's 2 batches
    const int b1 = b0 + 1;
    float4 A0 = make_float4(0.f, 0.f, 0.f, 0.f);
    float4 A1 = A0;

    const int NJ = NBUK / NX;
    for (int j = 0; j < NJ; ++j) {
        const int k = x + j * NX;
        const int o0 = boff[b0 * (NBUK + 1) + k];
        const int o1 = boff[b0 * (NBUK + 1) + k + 1];
        acc_range(emb, btok, b0 * SEQ, o0, o1, c, A0);
        const int p0 = boff[b1 * (NBUK + 1) + k];
        const int p1 = boff[b1 * (NBUK + 1) + k + 1];
        acc_range(emb, btok, b1 * SEQ, p0, p1, c, A1);
    }
    ((float4*)(partial + ((size_t)x * BATCH + b0) * EMB))[c] = A0;
    ((float4*)(partial + ((size_t)x * BATCH + b1) * EMB))[c] = A1;
}

// ---------------- Kernel 3: combine partials + fc1 + relu --------------------
// Grid (BATCH/GBM, 4). Block handles 16 batches x 128 hidden cols.
// W1 traffic: 256 blocks x 153.6 KB = 39 MB (vs 314 MB at GB=2).
__global__ __launch_bounds__(512) void fc1_kernel(
    const float* __restrict__ partial, // [NX, BATCH, EMB]
    const int* __restrict__ lengths,   // [BATCH]
    const float* __restrict__ W1,      // [EMB, HIDDEN]
    const float* __restrict__ b1,      // [HIDDEN]
    float* __restrict__ hbuf,          // [BATCH, HIDDEN]
    int NX)
{
    __shared__ float pT[EMB][GBM];     // 19.2 KB
    const int b0  = blockIdx.x * GBM;
    const int tid = threadIdx.x;

    for (int i = tid; i < EMB * GBM; i += 512) {
        const int g = i / EMB;
        const int e = i - g * EMB;
        float s = 0.f;
        for (int ns = 0; ns < NX; ++ns)
            s += partial[((size_t)ns * BATCH + b0 + g) * EMB + e];
        pT[e][g] = s / (float)lengths[b0 + g];
    }
    __syncthreads();

    const int jq = tid & 127;
    const int gs = tid >> 7;           // 0..3 -> batches b0+gs*4 .. +3
    const int j  = blockIdx.y * 128 + jq;
    const float bias = b1[j];
    float4 acc = make_float4(bias, bias, bias, bias);
#pragma unroll 4
    for (int e = 0; e < EMB; ++e) {
        const float  w = W1[(size_t)e * HIDDEN + j];
        const float4 p = *(const float4*)&pT[e][gs * 4];
        acc.x += p.x * w;
        acc.y += p.y * w;
        acc.z += p.z * w;
        acc.w += p.w * w;
    }
    hbuf[(size_t)(b0 + gs * 4 + 0) * HIDDEN + j] = fmaxf(acc.x, 0.f);
    hbuf[(size_t)(b0 + gs * 4 + 1) * HIDDEN + j] = fmaxf(acc.y, 0.f);
    hbuf[(size_t)(b0 + gs * 4 + 2) * HIDDEN + j] = fmaxf(acc.z, 0.f);
    hbuf[(size_t)(b0 + gs * 4 + 3) * HIDDEN + j] = fmaxf(acc.w, 0.f);
}

// ---------------- Kernel 4: fc2 (wave-per-row dot) ---------------------------
__global__ __launch_bounds__(256) void fc2_kernel(
    const float* __restrict__ hbuf,    // [BATCH, HIDDEN]
    const float* __restrict__ W2,      // [HIDDEN, 2]
    const float* __restrict__ b2,      // [2]
    float* __restrict__ out)           // [BATCH, 2]
{
    const int wave = threadIdx.x >> 6;
    const int lane = threadIdx.x & 63;
    const int b    = blockIdx.x * 4 + wave;

    const float4* hrow = (const float4*)(hbuf + (size_t)b * HIDDEN);
    const float4* W2v  = (const float4*)W2;
    float s0 = 0.f, s1 = 0.f;
#pragma unroll
    for (int q = 0; q < 2; ++q) {
        const int c = lane + q * 64;           // float4 chunk: jj = 4c..4c+3
        const float4 h  = hrow[c];
        const float4 wA = W2v[2 * c + 0];      // {(4c,0),(4c,1),(4c+1,0),(4c+1,1)}
        const float4 wB = W2v[2 * c + 1];
        s0 += h.x * wA.x + h.y * wA.z + h.z * wB.x + h.w * wB.z;
        s1 += h.x * wA.y + h.y * wA.w + h.z * wB.y + h.w * wB.w;
    }
#pragma unroll
    for (int off = 32; off > 0; off >>= 1) {
        s0 += __shfl_down(s0, off);
        s1 += __shfl_down(s1, off);
    }
    if (lane == 0) {
        out[b * 2 + 0] = s0 + b2[0];
        out[b * 2 + 1] = s1 + b2[1];
    }
}

extern "C" void kernel_launch(void* const* d_in, const int* in_sizes, int n_in,
                              void* d_out, int out_size, void* d_ws, size_t ws_size,
                              hipStream_t stream) {
    const int*   text    = (const int*)d_in[0];
    const int*   lengths = (const int*)d_in[1];
    const float* emb     = (const float*)d_in[2];
    const float* W1      = (const float*)d_in[3];
    const float* b1      = (const float*)d_in[4];
    const float* W2      = (const float*)d_in[5];
    const float* b2      = (const float*)d_in[6];
    float*       out     = (float*)d_out;

    char* ws = (char*)d_ws;
    const size_t btokBytes = (size_t)BATCH * SEQ * sizeof(int);           // 2 MB
    const size_t boffBytes = (size_t)BATCH * (NBUK + 1) * sizeof(int);    // 132 KB
    const size_t hbufBytes = (size_t)BATCH * HIDDEN * sizeof(float);      // 2 MB
    const size_t poolBytes = (size_t)BATCH * EMB * sizeof(float);         // 1.2 MB

    int*   btok = (int*)ws;
    int*   boff = (int*)(ws + btokBytes);
    float* partial = (float*)(ws + btokBytes + boffBytes);

    const size_t fixed = btokBytes + boffBytes + hbufBytes;
    int NX = 1;
    if      (ws_size >= fixed + 8 * poolBytes) NX = 8;
    else if (ws_size >= fixed + 4 * poolBytes) NX = 4;
    else if (ws_size >= fixed + 2 * poolBytes) NX = 2;
    float* hbuf = (float*)(ws + btokBytes + boffBytes + (size_t)NX * poolBytes);

    bucketize_kernel<<<BATCH / 4, 256, 0, stream>>>(text, lengths, btok, boff);
    pool_kernel<<<NX * (BATCH / GBATCH), 320, 0, stream>>>(btok, boff, emb, partial, NX);
    fc1_kernel<<<dim3(BATCH / GBM, 4), 512, 0, stream>>>(partial, lengths, W1, b1, hbuf, NX);
    fc2_kernel<<<BATCH / 4, 256, 0, stream>>>(hbuf, W2, b2, out);
}

// Round 5
// 89.793 us; speedup vs baseline: 1.1589x; 1.1589x over previous
//
#include <hip/hip_runtime.h>

constexpr int EMB    = 300;
constexpr int EMB4   = 75;     // EMB / 4 (float4 chunks per row)
constexpr int HIDDEN = 512;
constexpr int SEQ    = 512;
constexpr int BATCH  = 1024;
constexpr int VOCAB  = 50000;
constexpr int NBUK   = 32;     // vocab buckets
constexpr int BDIV   = 1563;   // ceil(50000/32); 49999/1563 = 31
constexpr int GBATCH = 8;      // batches per pool block
constexpr int GFC1   = 16;     // batches per fc1 block

__device__ __forceinline__ float4 f4add(float4 a, float4 b) {
    return make_float4(a.x + b.x, a.y + b.y, a.z + b.z, a.w + b.w);
}

// ---------------- Kernel 1: bucketize tokens per batch (deterministic) -------
__global__ __launch_bounds__(256) void bucketize_kernel(
    const int* __restrict__ text,      // [SEQ, BATCH]
    const int* __restrict__ lengths,   // [BATCH]
    int* __restrict__ btok,            // [BATCH, SEQ]
    int* __restrict__ boff)            // [BATCH, NBUK+1]
{
    const int wave = threadIdx.x >> 6;
    const int lane = threadIdx.x & 63;
    const int b    = blockIdx.x * 4 + wave;
    const int len  = lengths[b];
    const unsigned long long ltmask = (1ull << lane) - 1ull;

    int cnt = 0;
#pragma unroll
    for (int c = 0; c < 8; ++c) {
        const int s = c * 64 + lane;
        int k = NBUK;
        if (s < len) k = text[(size_t)s * BATCH + b] / BDIV;
        for (int kk = 0; kk < NBUK; ++kk) {
            const unsigned long long m = __ballot(k == kk);
            if (lane == kk) cnt += __popcll(m);
        }
    }
    int incl = cnt;
#pragma unroll
    for (int off = 1; off < 32; off <<= 1) {
        const int v = __shfl_up(incl, off);
        if (lane >= off && lane < NBUK) incl += v;
    }
    const int excl = incl - cnt;
    if (lane < NBUK)  boff[b * (NBUK + 1) + lane] = excl;
    if (lane == NBUK - 1) boff[b * (NBUK + 1) + NBUK] = incl;

    int base = excl;
#pragma unroll
    for (int c = 0; c < 8; ++c) {
        const int s = c * 64 + lane;
        int tok = 0, k = NBUK;
        if (s < len) { tok = text[(size_t)s * BATCH + b]; k = tok / BDIV; }
        unsigned long long mym = 0;
        int chunkcnt = 0;
        for (int kk = 0; kk < NBUK; ++kk) {
            const unsigned long long m = __ballot(k == kk);
            if (k == kk) mym = m;
            if (lane == kk) chunkcnt = __popcll(m);
        }
        const int rank = __popcll(mym & ltmask);
        const int pos  = __shfl(base, k) + rank;
        if (s < len) btok[(size_t)b * SEQ + pos] = tok;
        base += chunkcnt;
    }
}

// ---------------- Kernel 2: bucketed gather + pool (partial sums) ------------
__device__ __forceinline__ void acc_range(
    const float* __restrict__ emb, const int* __restrict__ btok,
    int base, int lo, int hi, int c, float4& A)
{
    int i = lo;
    for (; i + 4 <= hi; i += 4) {
        const int t0 = btok[base + i + 0];
        const int t1 = btok[base + i + 1];
        const int t2 = btok[base + i + 2];
        const int t3 = btok[base + i + 3];
        const float4 v0 = ((const float4*)(emb + (size_t)t0 * EMB))[c];
        const float4 v1 = ((const float4*)(emb + (size_t)t1 * EMB))[c];
        const float4 v2 = ((const float4*)(emb + (size_t)t2 * EMB))[c];
        const float4 v3 = ((const float4*)(emb + (size_t)t3 * EMB))[c];
        A = f4add(A, f4add(f4add(v0, v1), f4add(v2, v3)));
    }
    for (; i < hi; ++i) {
        const int t = btok[base + i];
        A = f4add(A, ((const float4*)(emb + (size_t)t * EMB))[c]);
    }
}

__global__ __launch_bounds__(320) void pool_kernel(
    const int* __restrict__ btok,      // [BATCH, SEQ] bucket-grouped
    const int* __restrict__ boff,      // [BATCH, NBUK+1]
    const float* __restrict__ emb,     // [VOCAB, EMB]
    float* __restrict__ partial,       // [NX, BATCH, EMB]
    int NX)
{
    const int x     = blockIdx.x % NX;
    const int g     = blockIdx.x / NX;
    const int group = threadIdx.x / 80;
    const int c     = threadIdx.x % 80;
    if (c >= EMB4) return;

    const int b0 = g * GBATCH + group * 2;
    const int b1 = b0 + 1;
    float4 A0 = make_float4(0.f, 0.f, 0.f, 0.f);
    float4 A1 = A0;

    const int NJ = NBUK / NX;
    for (int j = 0; j < NJ; ++j) {
        const int k = x + j * NX;
        const int o0 = boff[b0 * (NBUK + 1) + k];
        const int o1 = boff[b0 * (NBUK + 1) + k + 1];
        acc_range(emb, btok, b0 * SEQ, o0, o1, c, A0);
        const int p0 = boff[b1 * (NBUK + 1) + k];
        const int p1 = boff[b1 * (NBUK + 1) + k + 1];
        acc_range(emb, btok, b1 * SEQ, p0, p1, c, A1);
    }
    ((float4*)(partial + ((size_t)x * BATCH + b0) * EMB))[c] = A0;
    ((float4*)(partial + ((size_t)x * BATCH + b1) * EMB))[c] = A1;
}

// ---------------- Kernel 3: combine partials -> pooledT (transposed) ---------
// 76800 threads; thread (c,b) sums NX independent (unrolled) float4 loads,
// scales by 1/len, writes pooledT[4c+k][b] (coalesced over b).
template<int NX>
__global__ __launch_bounds__(256) void combine_kernel(
    const float* __restrict__ partial, // [NX, BATCH, EMB]
    const int* __restrict__ lengths,   // [BATCH]
    float* __restrict__ pooledT)       // [EMB, BATCH]
{
    const int t = blockIdx.x * 256 + threadIdx.x;
    const int b = t & (BATCH - 1);
    const int c = t >> 10;             // float4 chunk 0..74
    if (c >= EMB4) return;

    float4 s = make_float4(0.f, 0.f, 0.f, 0.f);
#pragma unroll
    for (int x = 0; x < NX; ++x) {
        const float4 v = *(const float4*)(partial + ((size_t)x * BATCH + b) * EMB + 4 * c);
        s = f4add(s, v);
    }
    const float inv = 1.0f / (float)lengths[b];
    pooledT[(size_t)(4 * c + 0) * BATCH + b] = s.x * inv;
    pooledT[(size_t)(4 * c + 1) * BATCH + b] = s.y * inv;
    pooledT[(size_t)(4 * c + 2) * BATCH + b] = s.z * inv;
    pooledT[(size_t)(4 * c + 3) * BATCH + b] = s.w * inv;
}

// ---------------- Kernel 4: fc1 + relu (no LDS, no barrier) ------------------
// Grid (BATCH/16, HIDDEN/64) = 512 blocks x 256 thr. Thread owns col j and a
// float4 of 4 batches. e-loop unrolled x10: 10 coalesced W1 loads + 10
// broadcast pooledT float4 loads in flight.
__global__ __launch_bounds__(256) void fc1_kernel(
    const float* __restrict__ pooledT, // [EMB, BATCH]
    const float* __restrict__ W1,      // [EMB, HIDDEN]
    const float* __restrict__ b1,      // [HIDDEN]
    float* __restrict__ hbuf)          // [BATCH, HIDDEN]
{
    const int j  = blockIdx.y * 64 + (threadIdx.x & 63);
    const int gs = threadIdx.x >> 6;                 // 0..3
    const int b0 = blockIdx.x * GFC1 + gs * 4;       // 4 batches (float4)

    const float bias = b1[j];
    float4 acc = make_float4(bias, bias, bias, bias);

    for (int e = 0; e < EMB; e += 10) {              // 300 = 30*10 exact
        const float w0 = W1[(size_t)(e + 0) * HIDDEN + j];
        const float w1 = W1[(size_t)(e + 1) * HIDDEN + j];
        const float w2 = W1[(size_t)(e + 2) * HIDDEN + j];
        const float w3 = W1[(size_t)(e + 3) * HIDDEN + j];
        const float w4 = W1[(size_t)(e + 4) * HIDDEN + j];
        const float w5 = W1[(size_t)(e + 5) * HIDDEN + j];
        const float w6 = W1[(size_t)(e + 6) * HIDDEN + j];
        const float w7 = W1[(size_t)(e + 7) * HIDDEN + j];
        const float w8 = W1[(size_t)(e + 8) * HIDDEN + j];
        const float w9 = W1[(size_t)(e + 9) * HIDDEN + j];
        const float4 p0 = *(const float4*)(pooledT + (size_t)(e + 0) * BATCH + b0);
        const float4 p1 = *(const float4*)(pooledT + (size_t)(e + 1) * BATCH + b0);
        const float4 p2 = *(const float4*)(pooledT + (size_t)(e + 2) * BATCH + b0);
        const float4 p3 = *(const float4*)(pooledT + (size_t)(e + 3) * BATCH + b0);
        const float4 p4 = *(const float4*)(pooledT + (size_t)(e + 4) * BATCH + b0);
        const float4 p5 = *(const float4*)(pooledT + (size_t)(e + 5) * BATCH + b0);
        const float4 p6 = *(const float4*)(pooledT + (size_t)(e + 6) * BATCH + b0);
        const float4 p7 = *(const float4*)(pooledT + (size_t)(e + 7) * BATCH + b0);
        const float4 p8 = *(const float4*)(pooledT + (size_t)(e + 8) * BATCH + b0);
        const float4 p9 = *(const float4*)(pooledT + (size_t)(e + 9) * BATCH + b0);
        acc.x += p0.x * w0 + p1.x * w1 + p2.x * w2 + p3.x * w3 + p4.x * w4
               + p5.x * w5 + p6.x * w6 + p7.x * w7 + p8.x * w8 + p9.x * w9;
        acc.y += p0.y * w0 + p1.y * w1 + p2.y * w2 + p3.y * w3 + p4.y * w4
               + p5.y * w5 + p6.y * w6 + p7.y * w7 + p8.y * w8 + p9.y * w9;
        acc.z += p0.z * w0 + p1.z * w1 + p2.z * w2 + p3.z * w3 + p4.z * w4
               + p5.z * w5 + p6.z * w6 + p7.z * w7 + p8.z * w8 + p9.z * w9;
        acc.w += p0.w * w0 + p1.w * w1 + p2.w * w2 + p3.w * w3 + p4.w * w4
               + p5.w * w5 + p6.w * w6 + p7.w * w7 + p8.w * w8 + p9.w * w9;
    }
    hbuf[(size_t)(b0 + 0) * HIDDEN + j] = fmaxf(acc.x, 0.f);
    hbuf[(size_t)(b0 + 1) * HIDDEN + j] = fmaxf(acc.y, 0.f);
    hbuf[(size_t)(b0 + 2) * HIDDEN + j] = fmaxf(acc.z, 0.f);
    hbuf[(size_t)(b0 + 3) * HIDDEN + j] = fmaxf(acc.w, 0.f);
}

// ---------------- Kernel 5: fc2 (wave-per-row dot) ---------------------------
__global__ __launch_bounds__(256) void fc2_kernel(
    const float* __restrict__ hbuf,    // [BATCH, HIDDEN]
    const float* __restrict__ W2,      // [HIDDEN, 2]
    const float* __restrict__ b2,      // [2]
    float* __restrict__ out)           // [BATCH, 2]
{
    const int wave = threadIdx.x >> 6;
    const int lane = threadIdx.x & 63;
    const int b    = blockIdx.x * 4 + wave;

    const float4* hrow = (const float4*)(hbuf + (size_t)b * HIDDEN);
    const float4* W2v  = (const float4*)W2;
    float s0 = 0.f, s1 = 0.f;
#pragma unroll
    for (int q = 0; q < 2; ++q) {
        const int c = lane + q * 64;
        const float4 h  = hrow[c];
        const float4 wA = W2v[2 * c + 0];
        const float4 wB = W2v[2 * c + 1];
        s0 += h.x * wA.x + h.y * wA.z + h.z * wB.x + h.w * wB.z;
        s1 += h.x * wA.y + h.y * wA.w + h.z * wB.y + h.w * wB.w;
    }
#pragma unroll
    for (int off = 32; off > 0; off >>= 1) {
        s0 += __shfl_down(s0, off);
        s1 += __shfl_down(s1, off);
    }
    if (lane == 0) {
        out[b * 2 + 0] = s0 + b2[0];
        out[b * 2 + 1] = s1 + b2[1];
    }
}

extern "C" void kernel_launch(void* const* d_in, const int* in_sizes, int n_in,
                              void* d_out, int out_size, void* d_ws, size_t ws_size,
                              hipStream_t stream) {
    const int*   text    = (const int*)d_in[0];
    const int*   lengths = (const int*)d_in[1];
    const float* emb     = (const float*)d_in[2];
    const float* W1      = (const float*)d_in[3];
    const float* b1      = (const float*)d_in[4];
    const float* W2      = (const float*)d_in[5];
    const float* b2      = (const float*)d_in[6];
    float*       out     = (float*)d_out;

    char* ws = (char*)d_ws;
    const size_t btokBytes = (size_t)BATCH * SEQ * sizeof(int);           // 2 MB
    const size_t boffBytes = (size_t)BATCH * (NBUK + 1) * sizeof(int);    // 132 KB
    const size_t poolBytes = (size_t)BATCH * EMB * sizeof(float);         // 1.2 MB
    const size_t pTBytes   = poolBytes;                                   // 1.2 MB
    const size_t hbufBytes = (size_t)BATCH * HIDDEN * sizeof(float);      // 2 MB

    int*   btok = (int*)ws;
    int*   boff = (int*)(ws + btokBytes);
    float* partial = (float*)(ws + btokBytes + boffBytes);

    const size_t fixed = btokBytes + boffBytes + pTBytes + hbufBytes;
    int NX = 1;
    if      (ws_size >= fixed + 8 * poolBytes) NX = 8;
    else if (ws_size >= fixed + 4 * poolBytes) NX = 4;
    else if (ws_size >= fixed + 2 * poolBytes) NX = 2;
    float* pooledT = (float*)(ws + btokBytes + boffBytes + (size_t)NX * poolBytes);
    float* hbuf    = pooledT + (size_t)BATCH * EMB;

    bucketize_kernel<<<BATCH / 4, 256, 0, stream>>>(text, lengths, btok, boff);
    pool_kernel<<<NX * (BATCH / GBATCH), 320, 0, stream>>>(btok, boff, emb, partial, NX);

    const int cgrid = (BATCH * EMB4 + 255) / 256;    // 300 blocks
    switch (NX) {
        case 8: combine_kernel<8><<<cgrid, 256, 0, stream>>>(partial, lengths, pooledT); break;
        case 4: combine_kernel<4><<<cgrid, 256, 0, stream>>>(partial, lengths, pooledT); break;
        case 2: combine_kernel<2><<<cgrid, 256, 0, stream>>>(partial, lengths, pooledT); break;
        default: combine_kernel<1><<<cgrid, 256, 0, stream>>>(partial, lengths, pooledT); break;
    }

    fc1_kernel<<<dim3(BATCH / GFC1, HIDDEN / 64), 256, 0, stream>>>(pooledT, W1, b1, hbuf);
    fc2_kernel<<<BATCH / 4, 256, 0, stream>>>(hbuf, W2, b2, out);
}

// Round 6
// 72.913 us; speedup vs baseline: 1.4272x; 1.2315x over previous
//
#include <hip/hip_runtime.h>

constexpr int EMB    = 300;
constexpr int EMB4   = 75;     // EMB / 4 (float4 chunks per row)
constexpr int HIDDEN = 512;
constexpr int SEQ    = 512;
constexpr int BATCH  = 1024;
constexpr int VOCAB  = 50000;
constexpr int NBUK   = 32;     // vocab buckets
constexpr int BDIV   = 1563;   // ceil(50000/32); 49999/1563 = 31
constexpr int PB     = 4;      // batches per pool block
constexpr int GFC1   = 16;     // batches per fc1 block

__device__ __forceinline__ float4 f4add(float4 a, float4 b) {
    return make_float4(a.x + b.x, a.y + b.y, a.z + b.z, a.w + b.w);
}

// ---------------- Kernel 1: bucketize tokens per batch (deterministic) -------
// (unchanged from R4/R5 — verified correct)
__global__ __launch_bounds__(256) void bucketize_kernel(
    const int* __restrict__ text,      // [SEQ, BATCH]
    const int* __restrict__ lengths,   // [BATCH]
    int* __restrict__ btok,            // [BATCH, SEQ]
    int* __restrict__ boff)            // [BATCH, NBUK+1]
{
    const int wave = threadIdx.x >> 6;
    const int lane = threadIdx.x & 63;
    const int b    = blockIdx.x * 4 + wave;
    const int len  = lengths[b];
    const unsigned long long ltmask = (1ull << lane) - 1ull;

    int cnt = 0;
#pragma unroll
    for (int c = 0; c < 8; ++c) {
        const int s = c * 64 + lane;
        int k = NBUK;
        if (s < len) k = text[(size_t)s * BATCH + b] / BDIV;
        for (int kk = 0; kk < NBUK; ++kk) {
            const unsigned long long m = __ballot(k == kk);
            if (lane == kk) cnt += __popcll(m);
        }
    }
    int incl = cnt;
#pragma unroll
    for (int off = 1; off < 32; off <<= 1) {
        const int v = __shfl_up(incl, off);
        if (lane >= off && lane < NBUK) incl += v;
    }
    const int excl = incl - cnt;
    if (lane < NBUK)  boff[b * (NBUK + 1) + lane] = excl;
    if (lane == NBUK - 1) boff[b * (NBUK + 1) + NBUK] = incl;

    int base = excl;
#pragma unroll
    for (int c = 0; c < 8; ++c) {
        const int s = c * 64 + lane;
        int tok = 0, k = NBUK;
        if (s < len) { tok = text[(size_t)s * BATCH + b]; k = tok / BDIV; }
        unsigned long long mym = 0;
        int chunkcnt = 0;
        for (int kk = 0; kk < NBUK; ++kk) {
            const unsigned long long m = __ballot(k == kk);
            if (k == kk) mym = m;
            if (lane == kk) chunkcnt = __popcll(m);
        }
        const int rank = __popcll(mym & ltmask);
        const int pos  = __shfl(base, k) + rank;
        if (s < len) btok[(size_t)b * SEQ + pos] = tok;
        base += chunkcnt;
    }
}

// ---------------- Kernel 2: bucketed gather + pool v6 ------------------------
// Slot x owns CONTIGUOUS buckets [x*NJ, (x+1)*NJ) -> one contiguous btok range
// per (batch, slot): a single long segment (avg ~32 tokens) instead of NJ
// fragments. 4 batches/block; thread (g,c) accumulates chunk c of batch b0+g
// with an 8-deep independent-load unroll (8 float4 = 128 B in flight).
__global__ __launch_bounds__(320) void pool_kernel(
    const int* __restrict__ btok,      // [BATCH, SEQ] bucket-grouped
    const int* __restrict__ boff,      // [BATCH, NBUK+1]
    const float* __restrict__ emb,     // [VOCAB, EMB]
    float* __restrict__ partial,       // [NX, BATCH, EMB]
    int NX)
{
    const int x  = blockIdx.x % NX;    // slot ~ XCD (round-robin dispatch)
    const int b0 = (blockIdx.x / NX) * PB;
    const int NJ = NBUK / NX;

    __shared__ int toks[PB][SEQ];
    __shared__ int seg[PB][2];         // lo, n

    if (threadIdx.x < PB) {
        const int b  = b0 + threadIdx.x;
        const int lo = boff[b * (NBUK + 1) + x * NJ];
        const int hi = boff[b * (NBUK + 1) + x * NJ + NJ];
        seg[threadIdx.x][0] = lo;
        seg[threadIdx.x][1] = hi - lo;
    }
    __syncthreads();

    for (int g = 0; g < PB; ++g) {
        const int lo = seg[g][0], n = seg[g][1];
        for (int t = threadIdx.x; t < n; t += 320)
            toks[g][t] = btok[(size_t)(b0 + g) * SEQ + lo + t];
    }
    __syncthreads();

    const int g = threadIdx.x / 80;
    const int c = threadIdx.x % 80;
    if (c < EMB4) {
        const int n = seg[g][1];
        float4 A = make_float4(0.f, 0.f, 0.f, 0.f);
        float4 B = A;
        int i = 0;
        for (; i + 8 <= n; i += 8) {
            const int t0 = toks[g][i + 0];
            const int t1 = toks[g][i + 1];
            const int t2 = toks[g][i + 2];
            const int t3 = toks[g][i + 3];
            const int t4 = toks[g][i + 4];
            const int t5 = toks[g][i + 5];
            const int t6 = toks[g][i + 6];
            const int t7 = toks[g][i + 7];
            const float4 v0 = ((const float4*)(emb + (size_t)t0 * EMB))[c];
            const float4 v1 = ((const float4*)(emb + (size_t)t1 * EMB))[c];
            const float4 v2 = ((const float4*)(emb + (size_t)t2 * EMB))[c];
            const float4 v3 = ((const float4*)(emb + (size_t)t3 * EMB))[c];
            const float4 v4 = ((const float4*)(emb + (size_t)t4 * EMB))[c];
            const float4 v5 = ((const float4*)(emb + (size_t)t5 * EMB))[c];
            const float4 v6 = ((const float4*)(emb + (size_t)t6 * EMB))[c];
            const float4 v7 = ((const float4*)(emb + (size_t)t7 * EMB))[c];
            A = f4add(A, f4add(f4add(v0, v1), f4add(v2, v3)));
            B = f4add(B, f4add(f4add(v4, v5), f4add(v6, v7)));
        }
        for (; i + 4 <= n; i += 4) {
            const float4 v0 = ((const float4*)(emb + (size_t)toks[g][i + 0] * EMB))[c];
            const float4 v1 = ((const float4*)(emb + (size_t)toks[g][i + 1] * EMB))[c];
            const float4 v2 = ((const float4*)(emb + (size_t)toks[g][i + 2] * EMB))[c];
            const float4 v3 = ((const float4*)(emb + (size_t)toks[g][i + 3] * EMB))[c];
            A = f4add(A, f4add(f4add(v0, v1), f4add(v2, v3)));
        }
        for (; i < n; ++i)
            B = f4add(B, ((const float4*)(emb + (size_t)toks[g][i] * EMB))[c]);
        A = f4add(A, B);
        ((float4*)(partial + ((size_t)x * BATCH + b0 + g) * EMB))[c] = A;
    }
}

// ---------------- Kernel 3: fused combine + fc1 + relu -----------------------
// Grid (BATCH/16, HIDDEN/128), 512 thr. Staging sums NX partials (unrolled)
// into pQ[quad][e] (float4 over 4 batches; aligned LDS reads, broadcast per
// wave). fc1: thread (j, gs) -> 10-unrolled e-loop, 10 W1 loads in flight.
template<int NX>
__global__ __launch_bounds__(512) void fc1_kernel(
    const float* __restrict__ partial, // [NX, BATCH, EMB]
    const int* __restrict__ lengths,   // [BATCH]
    const float* __restrict__ W1,      // [EMB, HIDDEN]
    const float* __restrict__ b1,      // [HIDDEN]
    float* __restrict__ hbuf)          // [BATCH, HIDDEN]
{
    __shared__ float4 pQ[GFC1 / 4][EMB];   // 19.2 KB: [quad][e] = 4 batches
    const int b0  = blockIdx.x * GFC1;
    const int tid = threadIdx.x;

    float* pQf = (float*)pQ;
    for (int i = tid; i < EMB * GFC1; i += 512) {
        const int g = i / EMB;             // batch 0..15 (consecutive tid -> consecutive e)
        const int e = i - g * EMB;
        float s = 0.f;
#pragma unroll
        for (int xx = 0; xx < NX; ++xx)
            s += partial[((size_t)xx * BATCH + b0 + g) * EMB + e];
        // element (g,e) -> pQ[g/4][e].component(g%4)
        pQf[((g >> 2) * EMB + e) * 4 + (g & 3)] = s / (float)lengths[b0 + g];
    }
    __syncthreads();

    const int j  = blockIdx.y * 128 + (tid & 127);
    const int gs = tid >> 7;               // quad 0..3
    const float bias = b1[j];
    float4 acc = make_float4(bias, bias, bias, bias);

    for (int e = 0; e < EMB; e += 10) {    // 300 = 30*10 exact
        const float w0 = W1[(size_t)(e + 0) * HIDDEN + j];
        const float w1 = W1[(size_t)(e + 1) * HIDDEN + j];
        const float w2 = W1[(size_t)(e + 2) * HIDDEN + j];
        const float w3 = W1[(size_t)(e + 3) * HIDDEN + j];
        const float w4 = W1[(size_t)(e + 4) * HIDDEN + j];
        const float w5 = W1[(size_t)(e + 5) * HIDDEN + j];
        const float w6 = W1[(size_t)(e + 6) * HIDDEN + j];
        const float w7 = W1[(size_t)(e + 7) * HIDDEN + j];
        const float w8 = W1[(size_t)(e + 8) * HIDDEN + j];
        const float w9 = W1[(size_t)(e + 9) * HIDDEN + j];
        const float4 p0 = pQ[gs][e + 0];
        const float4 p1 = pQ[gs][e + 1];
        const float4 p2 = pQ[gs][e + 2];
        const float4 p3 = pQ[gs][e + 3];
        const float4 p4 = pQ[gs][e + 4];
        const float4 p5 = pQ[gs][e + 5];
        const float4 p6 = pQ[gs][e + 6];
        const float4 p7 = pQ[gs][e + 7];
        const float4 p8 = pQ[gs][e + 8];
        const float4 p9 = pQ[gs][e + 9];
        acc.x += p0.x * w0 + p1.x * w1 + p2.x * w2 + p3.x * w3 + p4.x * w4
               + p5.x * w5 + p6.x * w6 + p7.x * w7 + p8.x * w8 + p9.x * w9;
        acc.y += p0.y * w0 + p1.y * w1 + p2.y * w2 + p3.y * w3 + p4.y * w4
               + p5.y * w5 + p6.y * w6 + p7.y * w7 + p8.y * w8 + p9.y * w9;
        acc.z += p0.z * w0 + p1.z * w1 + p2.z * w2 + p3.z * w3 + p4.z * w4
               + p5.z * w5 + p6.z * w6 + p7.z * w7 + p8.z * w8 + p9.z * w9;
        acc.w += p0.w * w0 + p1.w * w1 + p2.w * w2 + p3.w * w3 + p4.w * w4
               + p5.w * w5 + p6.w * w6 + p7.w * w7 + p8.w * w8 + p9.w * w9;
    }
    const int bb = b0 + gs * 4;
    hbuf[(size_t)(bb + 0) * HIDDEN + j] = fmaxf(acc.x, 0.f);
    hbuf[(size_t)(bb + 1) * HIDDEN + j] = fmaxf(acc.y, 0.f);
    hbuf[(size_t)(bb + 2) * HIDDEN + j] = fmaxf(acc.z, 0.f);
    hbuf[(size_t)(bb + 3) * HIDDEN + j] = fmaxf(acc.w, 0.f);
}

// ---------------- Kernel 4: fc2 (wave-per-row dot) ---------------------------
__global__ __launch_bounds__(256) void fc2_kernel(
    const float* __restrict__ hbuf,    // [BATCH, HIDDEN]
    const float* __restrict__ W2,      // [HIDDEN, 2]
    const float* __restrict__ b2,      // [2]
    float* __restrict__ out)           // [BATCH, 2]
{
    const int wave = threadIdx.x >> 6;
    const int lane = threadIdx.x & 63;
    const int b    = blockIdx.x * 4 + wave;

    const float4* hrow = (const float4*)(hbuf + (size_t)b * HIDDEN);
    const float4* W2v  = (const float4*)W2;
    float s0 = 0.f, s1 = 0.f;
#pragma unroll
    for (int q = 0; q < 2; ++q) {
        const int c = lane + q * 64;
        const float4 h  = hrow[c];
        const float4 wA = W2v[2 * c + 0];
        const float4 wB = W2v[2 * c + 1];
        s0 += h.x * wA.x + h.y * wA.z + h.z * wB.x + h.w * wB.z;
        s1 += h.x * wA.y + h.y * wA.w + h.z * wB.y + h.w * wB.w;
    }
#pragma unroll
    for (int off = 32; off > 0; off >>= 1) {
        s0 += __shfl_down(s0, off);
        s1 += __shfl_down(s1, off);
    }
    if (lane == 0) {
        out[b * 2 + 0] = s0 + b2[0];
        out[b * 2 + 1] = s1 + b2[1];
    }
}

extern "C" void kernel_launch(void* const* d_in, const int* in_sizes, int n_in,
                              void* d_out, int out_size, void* d_ws, size_t ws_size,
                              hipStream_t stream) {
    const int*   text    = (const int*)d_in[0];
    const int*   lengths = (const int*)d_in[1];
    const float* emb     = (const float*)d_in[2];
    const float* W1      = (const float*)d_in[3];
    const float* b1      = (const float*)d_in[4];
    const float* W2      = (const float*)d_in[5];
    const float* b2      = (const float*)d_in[6];
    float*       out     = (float*)d_out;

    char* ws = (char*)d_ws;
    const size_t btokBytes = (size_t)BATCH * SEQ * sizeof(int);           // 2 MB
    const size_t boffBytes = (size_t)BATCH * (NBUK + 1) * sizeof(int);    // 132 KB
    const size_t poolBytes = (size_t)BATCH * EMB * sizeof(float);         // 1.2 MB
    const size_t hbufBytes = (size_t)BATCH * HIDDEN * sizeof(float);      // 2 MB

    int*   btok = (int*)ws;
    int*   boff = (int*)(ws + btokBytes);
    float* partial = (float*)(ws + btokBytes + boffBytes);

    const size_t fixed = btokBytes + boffBytes + hbufBytes;
    int NX = 1;
    if      (ws_size >= fixed + 8 * poolBytes) NX = 8;
    else if (ws_size >= fixed + 4 * poolBytes) NX = 4;
    else if (ws_size >= fixed + 2 * poolBytes) NX = 2;
    float* hbuf = (float*)(ws + btokBytes + boffBytes + (size_t)NX * poolBytes);

    bucketize_kernel<<<BATCH / 4, 256, 0, stream>>>(text, lengths, btok, boff);
    pool_kernel<<<NX * (BATCH / PB), 320, 0, stream>>>(btok, boff, emb, partial, NX);

    dim3 fgrid(BATCH / GFC1, HIDDEN / 128);
    switch (NX) {
        case 8: fc1_kernel<8><<<fgrid, 512, 0, stream>>>(partial, lengths, W1, b1, hbuf); break;
        case 4: fc1_kernel<4><<<fgrid, 512, 0, stream>>>(partial, lengths, W1, b1, hbuf); break;
        case 2: fc1_kernel<2><<<fgrid, 512, 0, stream>>>(partial, lengths, W1, b1, hbuf); break;
        default: fc1_kernel<1><<<fgrid, 512, 0, stream>>>(partial, lengths, W1, b1, hbuf); break;
    }
    fc2_kernel<<<BATCH / 4, 256, 0, stream>>>(hbuf, W2, b2, out);
}